// Round 1
// baseline (264.417 us; speedup 1.0000x reference)
//
#include <hip/hip_runtime.h>

typedef __attribute__((ext_vector_type(8))) short short8;
typedef __attribute__((ext_vector_type(4))) float floatx4;

__device__ inline unsigned short f2bf(float f) {
    unsigned u = __float_as_uint(f);
    u += 0x7fffu + ((u >> 16) & 1u);   // round-to-nearest-even
    return (unsigned short)(u >> 16);
}

__device__ inline short8 pack8(const float4 a, const float4 b) {
    short8 r;
    r[0] = (short)f2bf(a.x); r[1] = (short)f2bf(a.y);
    r[2] = (short)f2bf(a.z); r[3] = (short)f2bf(a.w);
    r[4] = (short)f2bf(b.x); r[5] = (short)f2bf(b.y);
    r[6] = (short)f2bf(b.z); r[7] = (short)f2bf(b.w);
    return r;
}

// 256-node chunks: chunk id = tgt>>8 (derivable, no bits stored).
// packed word = (src<<16) | tgt     [requires src,tgt < 65536]
// per-chunk bin capacity: mean E*256/N = 4096, sigma ~64; 6144 = +32 sigma.
#define CHUNK_CAP 6144
#define BTILE 4096

// ---------------- combined: edge binning (blocks < nbin)  ||  layer-0 GEMM ----------------
// GEMM part fuses x0 construction (attr/cc/bl/ex -> bf16 tile in LDS) and
// on-the-fly W_in fp32->bf16 fragment conversion: out = relu(x0 @ W_in^T + b_in).

__global__ __launch_bounds__(256, 3) void gemm0_bin(
    const float* __restrict__ attr, const float* __restrict__ cc,
    const float* __restrict__ bl, const float* __restrict__ ex,
    const float* __restrict__ Wf, const float* __restrict__ bias,
    unsigned short* __restrict__ out_bf,
    const int* __restrict__ e, int* __restrict__ cursor,
    unsigned* __restrict__ packed_out,
    int N, int ATTR, int E, int nbin) {
    __shared__ __align__(16) char smem[2 * BTILE * 4 + 4 * 256 * 4];  // 36 KB
    int t = threadIdx.x;

    if ((int)blockIdx.x < nbin) {
        // ---- one 4096-edge binning tile ----
        unsigned* buf  = (unsigned*)smem;
        unsigned* sbuf = buf + BTILE;
        int* hist  = (int*)(sbuf + BTILE);
        int* offs  = hist + 256;
        int* gbase = offs + 256;
        int* lcur  = gbase + 256;
        int e0 = blockIdx.x * BTILE;
        int cnt = min(BTILE, E - e0);
        hist[t] = 0;
        __syncthreads();
        for (int j = t; j < cnt; j += 256) {
            unsigned src = (unsigned)e[e0 + j];
            unsigned tgt = (unsigned)e[E + e0 + j];
            buf[j] = (src << 16) | tgt;
            atomicAdd(&hist[tgt >> 8], 1);
        }
        __syncthreads();
        offs[t] = hist[t];
        __syncthreads();
        for (int o = 1; o < 256; o <<= 1) {
            int v = (t >= o) ? offs[t - o] : 0;
            __syncthreads();
            offs[t] += v;
            __syncthreads();
        }
        int excl = offs[t] - hist[t];
        offs[t] = excl;
        lcur[t] = excl;
        gbase[t] = (hist[t] > 0) ? t * CHUNK_CAP + atomicAdd(&cursor[t], hist[t]) : 0;
        __syncthreads();
        for (int j = t; j < cnt; j += 256) {
            unsigned v = buf[j];
            int c = (v >> 8) & 0xFF;
            int p = atomicAdd(&lcur[c], 1);
            sbuf[p] = v;
        }
        __syncthreads();
        int wv = t >> 6, lane = t & 63;
        for (int c = wv; c < 256; c += 4) {
            int n = hist[c], lo = offs[c], gb = gbase[c];
            for (int j = lane; j < n; j += 64)
                packed_out[gb + j] = sbuf[lo + j];
        }
        return;
    }

    // ---- layer-0 GEMM ----
    unsigned short* lx = (unsigned short*)smem;   // 64 x 136 bf16 tile
    int lane = t & 63;
    int w = t >> 6;
    int node0 = ((int)blockIdx.x - nbin) * 64;
    int n_off = w * 32;
    int q = lane >> 4;
    int m16 = lane & 15;

    // B fragments: fp32 W -> bf16 in-register
    short8 bf[2][4];
    #pragma unroll
    for (int nt = 0; nt < 2; ++nt)
        #pragma unroll
        for (int kk = 0; kk < 4; ++kk) {
            const float* p = Wf + (n_off + nt * 16 + m16) * 128 + kk * 32 + q * 8;
            bf[nt][kk] = pack8(*(const float4*)p, *(const float4*)(p + 4));
        }

    floatx4 acc[4][2];
    #pragma unroll
    for (int nt = 0; nt < 2; ++nt) {
        float bv = bias[n_off + nt * 16 + m16];
        floatx4 b4 = {bv, bv, bv, bv};
        #pragma unroll
        for (int mt = 0; mt < 4; ++mt) acc[mt][nt] = b4;
    }

    // stage x0 tile directly from raw inputs (fused build_x0)
    for (int i = 0; i < 32; ++i) {
        int idx = t + 256 * i;            // 0..8191 = 64 rows x 128 cols
        int nd = idx >> 7, col = idx & 127;
        int row = node0 + nd;
        float v = 0.0f;
        if (row < N) {
            if (col < ATTR)           v = attr[(size_t)row * ATTR + col];
            else if (col == ATTR)     v = cc[row];
            else if (col == ATTR + 1) v = bl[row];
            else                      v = ex[row];
        }
        lx[nd * 136 + col] = f2bf(v);
    }
    __syncthreads();

    #pragma unroll
    for (int kk = 0; kk < 4; ++kk) {
        short8 a[4];
        #pragma unroll
        for (int mt = 0; mt < 4; ++mt)
            a[mt] = *(const short8*)(lx + (mt * 16 + m16) * 136 + kk * 32 + q * 8);
        #pragma unroll
        for (int mt = 0; mt < 4; ++mt) {
            acc[mt][0] = __builtin_amdgcn_mfma_f32_16x16x32_bf16(a[mt], bf[0][kk], acc[mt][0], 0, 0, 0);
            acc[mt][1] = __builtin_amdgcn_mfma_f32_16x16x32_bf16(a[mt], bf[1][kk], acc[mt][1], 0, 0, 0);
        }
    }

    // epilogue: relu, bf16 out. C layout: col = lane&15, row = q*4 + r
    for (int mt = 0; mt < 4; ++mt) {
        int rbase = node0 + mt * 16 + q * 4;
        for (int r = 0; r < 4; ++r) {
            int rr = rbase + r;
            if (rr >= N) continue;
            for (int nt = 0; nt < 2; ++nt) {
                float v = fmaxf(acc[mt][nt][r], 0.0f);
                out_bf[(size_t)rr * 128 + n_off + nt * 16 + m16] = f2bf(v);
            }
        }
    }
}

// ---------------- per-chunk CSR finalize: 196 blocks, 256 nodes each ----------------

__global__ __launch_bounds__(256) void chunk_csr(const unsigned* __restrict__ packed,
                                                 const int* __restrict__ cursor,
                                                 uint2* __restrict__ rows2,
                                                 int* __restrict__ colv, int N) {
    __shared__ int hist[256], offs[256], lcnt[256];
    __shared__ int sbuf[CHUNK_CAP];
    int c = blockIdx.x;
    int base = c * CHUNK_CAP;
    int cnt = cursor[c];
    int t = threadIdx.x;
    hist[t] = 0;
    __syncthreads();
    for (int j = t; j < cnt; j += 256)
        atomicAdd(&hist[packed[base + j] & 255u], 1);
    __syncthreads();
    offs[t] = hist[t];
    __syncthreads();
    for (int o = 1; o < 256; o <<= 1) {
        int v = (t >= o) ? offs[t - o] : 0;
        __syncthreads();
        offs[t] += v;
        __syncthreads();
    }
    int excl = offs[t] - hist[t];
    offs[t] = excl;
    lcnt[t] = 0;
    __syncthreads();
    int node = c * 256 + t;
    if (node < N) {
        uint2 r;
        r.x = base + excl;
        r.y = base + excl + hist[t];
        rows2[node] = r;
    }
    for (int j = t; j < cnt; j += 256) {
        unsigned v = packed[base + j];
        int nd = v & 255u;
        int p = offs[nd] + atomicAdd(&lcnt[nd], 1);
        sbuf[p] = v >> 16;
    }
    __syncthreads();
    for (int j = t; j < cnt; j += 256) colv[base + j] = sbuf[j];
}

// ---------------- segment mean: one wave per node (unchanged, proven) ----------------

__global__ __launch_bounds__(256) void agg_mean(const unsigned short* __restrict__ x,
                                                const uint2* __restrict__ rows2,
                                                const int* __restrict__ colv,
                                                unsigned short* __restrict__ nm, int N) {
    int wid = (blockIdx.x * 256 + threadIdx.x) >> 6;
    int lane = threadIdx.x & 63;
    if (wid >= N) return;
    uint2 r = rows2[wid];
    int s0 = r.x, s1 = r.y;
    int deg = s1 - s0;
    int mn = deg < 64 ? deg : 64;
    int cvec = (lane < mn) ? colv[s0 + lane] : 0;
    int quarter = lane >> 4;       // 0..3: edges ei == quarter (mod 4)
    int cl = (lane & 15) * 8;      // this lane's 8-column group
    float a0 = 0.f, a1 = 0.f, a2 = 0.f, a3 = 0.f;
    float a4 = 0.f, a5 = 0.f, a6 = 0.f, a7 = 0.f;
    int lim = mn - 1;
    for (int j = 0; j < mn; j += 32) {
        uint4 v[8];
        #pragma unroll
        for (int u = 0; u < 8; ++u) {
            int ei = j + 4 * u + quarter;
            int idx = (ei <= lim) ? ei : lim;    // clamp: dup loads are cache hits
            int s = __shfl(cvec, idx, 64);
            v[u] = *(const uint4*)(x + (size_t)s * 128 + cl);
        }
        #pragma unroll
        for (int u = 0; u < 8; ++u) {
            int ei = j + 4 * u + quarter;
            if (ei <= lim) {                     // per-quarter predicate (cndmask)
                a0 += __uint_as_float(v[u].x << 16);
                a1 += __uint_as_float(v[u].x & 0xffff0000u);
                a2 += __uint_as_float(v[u].y << 16);
                a3 += __uint_as_float(v[u].y & 0xffff0000u);
                a4 += __uint_as_float(v[u].z << 16);
                a5 += __uint_as_float(v[u].z & 0xffff0000u);
                a6 += __uint_as_float(v[u].w << 16);
                a7 += __uint_as_float(v[u].w & 0xffff0000u);
            }
        }
    }
    for (int e = s0 + 64; e < s1; e += 4) {      // rare tail: deg > 64
        int ei = e + quarter;
        int idx = (ei < s1) ? ei : s1 - 1;
        int s = colv[idx];
        uint4 v = *(const uint4*)(x + (size_t)s * 128 + cl);
        if (ei < s1) {
            a0 += __uint_as_float(v.x << 16);
            a1 += __uint_as_float(v.x & 0xffff0000u);
            a2 += __uint_as_float(v.y << 16);
            a3 += __uint_as_float(v.y & 0xffff0000u);
            a4 += __uint_as_float(v.z << 16);
            a5 += __uint_as_float(v.z & 0xffff0000u);
            a6 += __uint_as_float(v.w << 16);
            a7 += __uint_as_float(v.w & 0xffff0000u);
        }
    }
    a0 += __shfl_xor(a0, 16, 64); a0 += __shfl_xor(a0, 32, 64);
    a1 += __shfl_xor(a1, 16, 64); a1 += __shfl_xor(a1, 32, 64);
    a2 += __shfl_xor(a2, 16, 64); a2 += __shfl_xor(a2, 32, 64);
    a3 += __shfl_xor(a3, 16, 64); a3 += __shfl_xor(a3, 32, 64);
    a4 += __shfl_xor(a4, 16, 64); a4 += __shfl_xor(a4, 32, 64);
    a5 += __shfl_xor(a5, 16, 64); a5 += __shfl_xor(a5, 32, 64);
    a6 += __shfl_xor(a6, 16, 64); a6 += __shfl_xor(a6, 32, 64);
    a7 += __shfl_xor(a7, 16, 64); a7 += __shfl_xor(a7, 32, 64);
    if (quarter == 0) {
        float inv = 1.0f / (float)(deg > 1 ? deg : 1);
        a0 *= inv; a1 *= inv; a2 *= inv; a3 *= inv;
        a4 *= inv; a5 *= inv; a6 *= inv; a7 *= inv;
        uint4 o;
        o.x = ((unsigned)f2bf(a1) << 16) | (unsigned)f2bf(a0);
        o.y = ((unsigned)f2bf(a3) << 16) | (unsigned)f2bf(a2);
        o.z = ((unsigned)f2bf(a5) << 16) | (unsigned)f2bf(a4);
        o.w = ((unsigned)f2bf(a7) << 16) | (unsigned)f2bf(a6);
        *(uint4*)(nm + (size_t)wid * 128 + cl) = o;
    }
}

// ---------------- 2-phase fused GEMM: out = act(X0*W0^T + X1*W1^T + b0 + b1) [*exist] ----
// fp32 weights converted to bf16 fragments in-register; biases fused in acc init.

__global__ __launch_bounds__(256, 3) void gemm_fused(
    const unsigned short* __restrict__ X0, const unsigned short* __restrict__ X1,
    const float* __restrict__ W0f, const float* __restrict__ W1f,
    const float* __restrict__ b0, const float* __restrict__ b1,
    const float* __restrict__ ex,
    unsigned short* __restrict__ obf, float* __restrict__ of32,
    int N, int relu) {
    __shared__ unsigned short lx[64 * 136];
    int tid = threadIdx.x;
    int lane = tid & 63;
    int w = tid >> 6;
    int node0 = blockIdx.x * 64;
    int n_off = w * 32;
    int q = lane >> 4;
    int m16 = lane & 15;

    short8 bf0[2][4], bf1[2][4];
    #pragma unroll
    for (int nt = 0; nt < 2; ++nt)
        #pragma unroll
        for (int kk = 0; kk < 4; ++kk) {
            const float* p0 = W0f + (n_off + nt * 16 + m16) * 128 + kk * 32 + q * 8;
            bf0[nt][kk] = pack8(*(const float4*)p0, *(const float4*)(p0 + 4));
            const float* p1 = W1f + (n_off + nt * 16 + m16) * 128 + kk * 32 + q * 8;
            bf1[nt][kk] = pack8(*(const float4*)p1, *(const float4*)(p1 + 4));
        }

    floatx4 acc[4][2];
    #pragma unroll
    for (int nt = 0; nt < 2; ++nt) {
        int col = n_off + nt * 16 + m16;
        float bv = b0[col] + b1[col];
        floatx4 b4 = {bv, bv, bv, bv};
        #pragma unroll
        for (int mt = 0; mt < 4; ++mt) acc[mt][nt] = b4;
    }

    for (int ph = 0; ph < 2; ++ph) {
        const unsigned short* X = ph ? X1 : X0;
        for (int i = 0; i < 4; ++i) {
            int c = tid + 256 * i;          // 16B chunk id, 0..1023
            int nd = c >> 4, ck = c & 15;
            short8 v = {0, 0, 0, 0, 0, 0, 0, 0};
            if (node0 + nd < N) v = *(const short8*)(X + (size_t)(node0 + nd) * 128 + ck * 8);
            *(short8*)(lx + nd * 136 + ck * 8) = v;
        }
        __syncthreads();
        #pragma unroll
        for (int kk = 0; kk < 4; ++kk) {
            short8 a[4];
            #pragma unroll
            for (int mt = 0; mt < 4; ++mt)
                a[mt] = *(const short8*)(lx + (mt * 16 + m16) * 136 + kk * 32 + q * 8);
            #pragma unroll
            for (int mt = 0; mt < 4; ++mt) {
                const short8* p0 = ph ? &bf1[0][kk] : &bf0[0][kk];
                const short8* p1 = ph ? &bf1[1][kk] : &bf0[1][kk];
                acc[mt][0] = __builtin_amdgcn_mfma_f32_16x16x32_bf16(a[mt], *p0, acc[mt][0], 0, 0, 0);
                acc[mt][1] = __builtin_amdgcn_mfma_f32_16x16x32_bf16(a[mt], *p1, acc[mt][1], 0, 0, 0);
            }
        }
        __syncthreads();
    }

    for (int mt = 0; mt < 4; ++mt) {
        int rbase = node0 + mt * 16 + q * 4;
        for (int r = 0; r < 4; ++r) {
            int rr = rbase + r;
            if (rr >= N) continue;
            float e = ex ? ex[rr] : 1.0f;
            for (int nt = 0; nt < 2; ++nt) {
                float v = acc[mt][nt][r];
                if (relu) v = fmaxf(v, 0.0f);
                v *= e;
                int col = n_off + nt * 16 + m16;
                if (obf) obf[(size_t)rr * 128 + col] = f2bf(v);
                else     of32[(size_t)rr * 128 + col] = v;
            }
        }
    }
}

// ---------------- launch ----------------

extern "C" void kernel_launch(void* const* d_in, const int* in_sizes, int n_in,
                              void* d_out, int out_size, void* d_ws, size_t ws_size,
                              hipStream_t stream) {
    const float* attr = (const float*)d_in[0];
    const float* cc   = (const float*)d_in[1];
    const float* bl   = (const float*)d_in[2];
    const float* ex   = (const float*)d_in[3];
    const float* w_in = (const float*)d_in[4];
    const float* b_in = (const float*)d_in[5];
    const float* w1s  = (const float*)d_in[6];
    const float* b1s  = (const float*)d_in[7];
    const float* w1n  = (const float*)d_in[8];
    const float* b1n  = (const float*)d_in[9];
    const float* w2s  = (const float*)d_in[10];
    const float* b2s  = (const float*)d_in[11];
    const float* w2n  = (const float*)d_in[12];
    const float* b2n  = (const float*)d_in[13];
    const int*   eidx = (const int*)d_in[14];

    int N = in_sizes[3];
    int ATTR = in_sizes[0] / N;
    int E = in_sizes[14] / 2;
    int Npad = ((N + 63) / 64) * 64;
    int nchunk = (N + 255) / 256;                  // 196 for N=50000 (must be <=256)
    int ntilesE = (E + BTILE - 1) / BTILE;         // 196
    int gblk = Npad / 64;                          // 782

    char* ws = (char*)d_ws;
    size_t off = 0;
    auto alloc = [&](size_t bytes) -> char* {
        off = (off + 255) & ~(size_t)255;
        char* p = ws + off;
        off += bytes;
        return p;
    };
    unsigned short* x1 = (unsigned short*)alloc((size_t)Npad * 128 * 2);
    unsigned short* x2 = (unsigned short*)alloc((size_t)Npad * 128 * 2);
    unsigned short* nm = (unsigned short*)alloc((size_t)Npad * 128 * 2);
    int* colv        = (int*)alloc((size_t)nchunk * CHUNK_CAP * 4);
    unsigned* packed = (unsigned*)alloc((size_t)nchunk * CHUNK_CAP * 4);
    uint2* rows2     = (uint2*)alloc((size_t)N * 8);
    int* cursor      = (int*)alloc(256 * 4);

    hipMemsetAsync(cursor, 0, 256 * sizeof(int), stream);

    // K1: edge binning (blocks 0..ntilesE-1)  ||  layer 0 GEMM (fused x0 build)
    gemm0_bin<<<ntilesE + gblk, 256, 0, stream>>>(attr, cc, bl, ex, w_in, b_in, x1,
                                                  eidx, cursor, packed,
                                                  N, ATTR, E, ntilesE);
    // K2: CSR finalize
    chunk_csr<<<nchunk, 256, 0, stream>>>(packed, cursor, rows2, colv, N);
    // K3: nm1 = segment_mean(x1)
    agg_mean<<<(N + 3) / 4, 256, 0, stream>>>(x1, rows2, colv, nm, N);
    // K4: x2 = relu(x1 @ W1s^T + nm1 @ W1n^T + b1s + b1n) * exist
    gemm_fused<<<gblk, 256, 0, stream>>>(x1, nm, w1s, w1n, b1s, b1n, ex,
                                         x2, (float*)nullptr, N, 1);
    // K5: nm2 = segment_mean(x2)
    agg_mean<<<(N + 3) / 4, 256, 0, stream>>>(x2, rows2, colv, nm, N);
    // K6: out = (x2 @ W2s^T + nm2 @ W2n^T + b2s + b2n) * exist   (fp32 out)
    gemm_fused<<<gblk, 256, 0, stream>>>(x2, nm, w2s, w2n, b2s, b2n, ex,
                                         (unsigned short*)nullptr, (float*)d_out, N, 0);
}

// Round 2
// 242.114 us; speedup vs baseline: 1.0921x; 1.0921x over previous
//
#include <hip/hip_runtime.h>

typedef __attribute__((ext_vector_type(8))) short short8;
typedef __attribute__((ext_vector_type(4))) float floatx4;

__device__ inline unsigned short f2bf(float f) {
    unsigned u = __float_as_uint(f);
    u += 0x7fffu + ((u >> 16) & 1u);   // round-to-nearest-even
    return (unsigned short)(u >> 16);
}

// 512-node chunks (R0-proven): chunk = tgt>>9, 98 chunks for N=50000.
// packed word: (chunk<<25) | (src<<9) | (tgt&511)   [src < 65536]
#define CHUNK_CAP 12288   // mean E/98 = 8163, sigma ~90; +45 sigma headroom
#define BTILE 4096
#define NPREP 256         // 4*16384/256 weight-convert blocks

// ---------------- K1: bin tiles | weight prep | layer-0 GEMM (fused x0 build) ------------

__global__ __launch_bounds__(256, 3) void gemm0_bin(
    const float* __restrict__ attr, const float* __restrict__ cc,
    const float* __restrict__ bl, const float* __restrict__ ex,
    const float* __restrict__ Wf, const float* __restrict__ bias,
    unsigned short* __restrict__ out_bf,
    const int* __restrict__ e, int* __restrict__ cursor,
    unsigned* __restrict__ packed_out,
    const float* __restrict__ w1s, const float* __restrict__ w1n,
    const float* __restrict__ w2s, const float* __restrict__ w2n,
    const float* __restrict__ b1s, const float* __restrict__ b1n,
    const float* __restrict__ b2s, const float* __restrict__ b2n,
    unsigned short* __restrict__ wb, float* __restrict__ biasf,
    int N, int ATTR, int E, int ntilesE, int nbin) {
    // layout: bin uses [buf 16K][sbuf 16K][hist/offs/gbase/lcur 2K] = 34K
    //         gemm uses [sflat 32000][lx 17408] = 49408
    __shared__ __align__(16) char smem[49408];
    int t = threadIdx.x;
    int bid = blockIdx.x;

    if (bid < nbin) {
        // ---- edge binning: 4096-edge tiles into 128 chunk bins ----
        unsigned* buf  = (unsigned*)smem;
        unsigned* sbuf = buf + BTILE;
        int* hist  = (int*)(sbuf + BTILE);
        int* offs  = hist + 128;
        int* gbase = offs + 128;
        int* lcur  = gbase + 128;
        for (int tile = bid; tile < ntilesE; tile += nbin) {
            int e0 = tile * BTILE;
            int cnt = min(BTILE, E - e0);
            if (t < 128) hist[t] = 0;
            __syncthreads();
            for (int j = t; j < cnt; j += 256) {
                unsigned src = (unsigned)e[e0 + j];
                unsigned tgt = (unsigned)e[E + e0 + j];
                unsigned c = tgt >> 9;
                buf[j] = (c << 25) | (src << 9) | (tgt & 511u);
                atomicAdd(&hist[c], 1);
            }
            __syncthreads();
            if (t < 128) offs[t] = hist[t];
            __syncthreads();
            for (int o = 1; o < 128; o <<= 1) {
                int v = (t < 128 && t >= o) ? offs[t - o] : 0;
                __syncthreads();
                if (t < 128) offs[t] += v;
                __syncthreads();
            }
            if (t < 128) {
                int excl = offs[t] - hist[t];
                offs[t] = excl;
                lcur[t] = excl;
                gbase[t] = (hist[t] > 0) ? t * CHUNK_CAP + atomicAdd(&cursor[t], hist[t]) : 0;
            }
            __syncthreads();
            for (int j = t; j < cnt; j += 256) {
                unsigned v = buf[j];
                int c = v >> 25;
                int p = atomicAdd(&lcur[c], 1);
                sbuf[p] = v;
            }
            __syncthreads();
            int wv = t >> 6, lane = t & 63;
            for (int c = wv; c < 128; c += 4) {
                int n = hist[c], lo = offs[c], gb = gbase[c];
                for (int j = lane; j < n; j += 64)
                    packed_out[gb + j] = sbuf[lo + j];
            }
            __syncthreads();
        }
        return;
    }

    if (bid < nbin + NPREP) {
        // ---- weight prep: w1s|w1n|w2s|w2n -> bf16, fused biases ----
        int pb = bid - nbin;
        int idx = pb * 256 + t;            // 0..65535
        int m = idx >> 14, j = idx & 16383;
        const float* src = (m == 0) ? w1s : (m == 1) ? w1n : (m == 2) ? w2s : w2n;
        wb[idx] = f2bf(src[j]);
        if (pb == 0 && t < 128) {
            biasf[t]       = b1s[t] + b1n[t];
            biasf[128 + t] = b2s[t] + b2n[t];
        }
        return;
    }

    // ---- layer-0 GEMM: out = relu(x0 @ W_in^T + b_in), x0 built in LDS ----
    float* sflat = (float*)smem;                               // 64 x ATTR fp32
    unsigned short* lx = (unsigned short*)(smem + 32000);      // 64 x 136 bf16
    int lane = t & 63;
    int w = t >> 6;
    int node0 = (bid - nbin - NPREP) * 64;
    int n_off = w * 32;
    int q = lane >> 4;
    int m16 = lane & 15;

    // stage attr slab as coalesced float4 (base = node0*ATTR*4, 16B-aligned for node0%4==0)
    int nrow = N - node0; nrow = nrow > 64 ? 64 : (nrow < 0 ? 0 : nrow);
    int nelem = nrow * ATTR;
    {
        const float* abase = attr + (size_t)node0 * ATTR;
        int nv = nelem >> 2;
        const float4* src4 = (const float4*)abase;
        for (int i = t; i < nv; i += 256) ((float4*)sflat)[i] = src4[i];
        for (int i = (nv << 2) + t; i < nelem; i += 256) sflat[i] = abase[i];
    }

    // B fragments: fp32 W_in -> bf16 in-register (64KB, L2-resident)
    short8 bf[2][4];
    #pragma unroll
    for (int nt = 0; nt < 2; ++nt)
        #pragma unroll
        for (int kk = 0; kk < 4; ++kk) {
            const float* p = Wf + (n_off + nt * 16 + m16) * 128 + kk * 32 + q * 8;
            float4 aa = *(const float4*)p, bb = *(const float4*)(p + 4);
            short8 r;
            r[0] = (short)f2bf(aa.x); r[1] = (short)f2bf(aa.y);
            r[2] = (short)f2bf(aa.z); r[3] = (short)f2bf(aa.w);
            r[4] = (short)f2bf(bb.x); r[5] = (short)f2bf(bb.y);
            r[6] = (short)f2bf(bb.z); r[7] = (short)f2bf(bb.w);
            bf[nt][kk] = r;
        }

    floatx4 acc[4][2];
    #pragma unroll
    for (int nt = 0; nt < 2; ++nt) {
        float bv = bias[n_off + nt * 16 + m16];
        floatx4 b4 = {bv, bv, bv, bv};
        #pragma unroll
        for (int mt = 0; mt < 4; ++mt) acc[mt][nt] = b4;
    }
    __syncthreads();

    // convert LDS fp32 slab + cc/bl/ex -> bf16 tile
    for (int i = 0; i < 32; ++i) {
        int idx = t + 256 * i;            // 64 rows x 128 cols
        int nd = idx >> 7, col = idx & 127;
        int row = node0 + nd;
        float v = 0.0f;
        if (row < N) {
            if (col < ATTR)           v = sflat[nd * ATTR + col];
            else if (col == ATTR)     v = cc[row];
            else if (col == ATTR + 1) v = bl[row];
            else                      v = ex[row];
        }
        lx[nd * 136 + col] = f2bf(v);
    }
    __syncthreads();

    #pragma unroll
    for (int kk = 0; kk < 4; ++kk) {
        short8 a[4];
        #pragma unroll
        for (int mt = 0; mt < 4; ++mt)
            a[mt] = *(const short8*)(lx + (mt * 16 + m16) * 136 + kk * 32 + q * 8);
        #pragma unroll
        for (int mt = 0; mt < 4; ++mt) {
            acc[mt][0] = __builtin_amdgcn_mfma_f32_16x16x32_bf16(a[mt], bf[0][kk], acc[mt][0], 0, 0, 0);
            acc[mt][1] = __builtin_amdgcn_mfma_f32_16x16x32_bf16(a[mt], bf[1][kk], acc[mt][1], 0, 0, 0);
        }
    }

    // epilogue: relu, bf16. C layout: col = lane&15, row = q*4 + r
    for (int mt = 0; mt < 4; ++mt) {
        int rbase = node0 + mt * 16 + q * 4;
        for (int r = 0; r < 4; ++r) {
            int rr = rbase + r;
            if (rr >= N) continue;
            for (int nt = 0; nt < 2; ++nt) {
                float v = fmaxf(acc[mt][nt][r], 0.0f);
                out_bf[(size_t)rr * 128 + n_off + nt * 16 + m16] = f2bf(v);
            }
        }
    }
}

// ---------------- K2: per-chunk CSR finalize (512 nodes/block, R0-proven) ----------------

__global__ __launch_bounds__(256) void chunk_csr(const unsigned* __restrict__ packed,
                                                 const int* __restrict__ cursor,
                                                 uint2* __restrict__ rows2,
                                                 int* __restrict__ colv, int N) {
    __shared__ int hist[512], offs[512], lcnt[512], pp[256];
    __shared__ int sbuf[CHUNK_CAP];
    int c = blockIdx.x;
    int base = c * CHUNK_CAP;
    int cnt = cursor[c];                 // relative count (cursor memset to 0)
    int t = threadIdx.x;
    hist[t] = 0;
    hist[t + 256] = 0;
    __syncthreads();
    for (int j = t; j < cnt; j += 256)
        atomicAdd(&hist[packed[base + j] & 511u], 1);
    __syncthreads();
    int a0 = hist[2 * t], a1 = hist[2 * t + 1];
    pp[t] = a0 + a1;
    __syncthreads();
    for (int o = 1; o < 256; o <<= 1) {
        int v = (t >= o) ? pp[t - o] : 0;
        __syncthreads();
        pp[t] += v;
        __syncthreads();
    }
    int excl = pp[t] - (a0 + a1);
    offs[2 * t] = excl;
    offs[2 * t + 1] = excl + a0;
    lcnt[2 * t] = 0;
    lcnt[2 * t + 1] = 0;
    __syncthreads();
    for (int j = t; j < 512; j += 256) {
        int node = c * 512 + j;
        if (node < N) {
            uint2 r;
            r.x = base + offs[j];
            r.y = base + offs[j] + hist[j];
            rows2[node] = r;
        }
    }
    for (int j = t; j < cnt; j += 256) {
        unsigned v = packed[base + j];
        int node = v & 511u;
        int p = offs[node] + atomicAdd(&lcnt[node], 1);
        sbuf[p] = (v >> 9) & 0xFFFFu;
    }
    __syncthreads();
    for (int j = t; j < cnt; j += 256) colv[base + j] = sbuf[j];
}

// ---------------- segment mean: one wave per node (unchanged, proven) ----------------

__global__ __launch_bounds__(256) void agg_mean(const unsigned short* __restrict__ x,
                                                const uint2* __restrict__ rows2,
                                                const int* __restrict__ colv,
                                                unsigned short* __restrict__ nm, int N) {
    int wid = (blockIdx.x * 256 + threadIdx.x) >> 6;
    int lane = threadIdx.x & 63;
    if (wid >= N) return;
    uint2 r = rows2[wid];
    int s0 = r.x, s1 = r.y;
    int deg = s1 - s0;
    int mn = deg < 64 ? deg : 64;
    int cvec = (lane < mn) ? colv[s0 + lane] : 0;
    int quarter = lane >> 4;
    int cl = (lane & 15) * 8;
    float a0 = 0.f, a1 = 0.f, a2 = 0.f, a3 = 0.f;
    float a4 = 0.f, a5 = 0.f, a6 = 0.f, a7 = 0.f;
    int lim = mn - 1;
    for (int j = 0; j < mn; j += 32) {
        uint4 v[8];
        #pragma unroll
        for (int u = 0; u < 8; ++u) {
            int ei = j + 4 * u + quarter;
            int idx = (ei <= lim) ? ei : lim;
            int s = __shfl(cvec, idx, 64);
            v[u] = *(const uint4*)(x + (size_t)s * 128 + cl);
        }
        #pragma unroll
        for (int u = 0; u < 8; ++u) {
            int ei = j + 4 * u + quarter;
            if (ei <= lim) {
                a0 += __uint_as_float(v[u].x << 16);
                a1 += __uint_as_float(v[u].x & 0xffff0000u);
                a2 += __uint_as_float(v[u].y << 16);
                a3 += __uint_as_float(v[u].y & 0xffff0000u);
                a4 += __uint_as_float(v[u].z << 16);
                a5 += __uint_as_float(v[u].z & 0xffff0000u);
                a6 += __uint_as_float(v[u].w << 16);
                a7 += __uint_as_float(v[u].w & 0xffff0000u);
            }
        }
    }
    for (int e = s0 + 64; e < s1; e += 4) {
        int ei = e + quarter;
        int idx = (ei < s1) ? ei : s1 - 1;
        int s = colv[idx];
        uint4 v = *(const uint4*)(x + (size_t)s * 128 + cl);
        if (ei < s1) {
            a0 += __uint_as_float(v.x << 16);
            a1 += __uint_as_float(v.x & 0xffff0000u);
            a2 += __uint_as_float(v.y << 16);
            a3 += __uint_as_float(v.y & 0xffff0000u);
            a4 += __uint_as_float(v.z << 16);
            a5 += __uint_as_float(v.z & 0xffff0000u);
            a6 += __uint_as_float(v.w << 16);
            a7 += __uint_as_float(v.w & 0xffff0000u);
        }
    }
    a0 += __shfl_xor(a0, 16, 64); a0 += __shfl_xor(a0, 32, 64);
    a1 += __shfl_xor(a1, 16, 64); a1 += __shfl_xor(a1, 32, 64);
    a2 += __shfl_xor(a2, 16, 64); a2 += __shfl_xor(a2, 32, 64);
    a3 += __shfl_xor(a3, 16, 64); a3 += __shfl_xor(a3, 32, 64);
    a4 += __shfl_xor(a4, 16, 64); a4 += __shfl_xor(a4, 32, 64);
    a5 += __shfl_xor(a5, 16, 64); a5 += __shfl_xor(a5, 32, 64);
    a6 += __shfl_xor(a6, 16, 64); a6 += __shfl_xor(a6, 32, 64);
    a7 += __shfl_xor(a7, 16, 64); a7 += __shfl_xor(a7, 32, 64);
    if (quarter == 0) {
        float inv = 1.0f / (float)(deg > 1 ? deg : 1);
        a0 *= inv; a1 *= inv; a2 *= inv; a3 *= inv;
        a4 *= inv; a5 *= inv; a6 *= inv; a7 *= inv;
        uint4 o;
        o.x = ((unsigned)f2bf(a1) << 16) | (unsigned)f2bf(a0);
        o.y = ((unsigned)f2bf(a3) << 16) | (unsigned)f2bf(a2);
        o.z = ((unsigned)f2bf(a5) << 16) | (unsigned)f2bf(a4);
        o.w = ((unsigned)f2bf(a7) << 16) | (unsigned)f2bf(a6);
        *(uint4*)(nm + (size_t)wid * 128 + cl) = o;
    }
}

// ---------------- 2-phase fused GEMM (R0 form: bf16 weights, fused bias) ----------------

__global__ __launch_bounds__(256, 3) void gemm_fused(
    const unsigned short* __restrict__ X0, const unsigned short* __restrict__ X1,
    const unsigned short* __restrict__ W0, const unsigned short* __restrict__ W1,
    const float* __restrict__ bias, const float* __restrict__ ex,
    unsigned short* __restrict__ obf, float* __restrict__ of32,
    int N, int relu) {
    __shared__ unsigned short lx[64 * 136];
    int tid = threadIdx.x;
    int lane = tid & 63;
    int w = tid >> 6;
    int node0 = blockIdx.x * 64;
    int n_off = w * 32;
    int q = lane >> 4;
    int m16 = lane & 15;

    short8 bf0[2][4], bf1[2][4];
    #pragma unroll
    for (int nt = 0; nt < 2; ++nt)
        #pragma unroll
        for (int kk = 0; kk < 4; ++kk) {
            bf0[nt][kk] = *(const short8*)(W0 + (n_off + nt * 16 + m16) * 128 + kk * 32 + q * 8);
            bf1[nt][kk] = *(const short8*)(W1 + (n_off + nt * 16 + m16) * 128 + kk * 32 + q * 8);
        }

    floatx4 acc[4][2];
    #pragma unroll
    for (int nt = 0; nt < 2; ++nt) {
        float bv = bias[n_off + nt * 16 + m16];
        floatx4 b4 = {bv, bv, bv, bv};
        #pragma unroll
        for (int mt = 0; mt < 4; ++mt) acc[mt][nt] = b4;
    }

    for (int ph = 0; ph < 2; ++ph) {
        const unsigned short* X = ph ? X1 : X0;
        for (int i = 0; i < 4; ++i) {
            int c = tid + 256 * i;
            int nd = c >> 4, ck = c & 15;
            short8 v = {0, 0, 0, 0, 0, 0, 0, 0};
            if (node0 + nd < N) v = *(const short8*)(X + (size_t)(node0 + nd) * 128 + ck * 8);
            *(short8*)(lx + nd * 136 + ck * 8) = v;
        }
        __syncthreads();
        #pragma unroll
        for (int kk = 0; kk < 4; ++kk) {
            short8 a[4];
            #pragma unroll
            for (int mt = 0; mt < 4; ++mt)
                a[mt] = *(const short8*)(lx + (mt * 16 + m16) * 136 + kk * 32 + q * 8);
            #pragma unroll
            for (int mt = 0; mt < 4; ++mt) {
                const short8* p0 = ph ? &bf1[0][kk] : &bf0[0][kk];
                const short8* p1 = ph ? &bf1[1][kk] : &bf0[1][kk];
                acc[mt][0] = __builtin_amdgcn_mfma_f32_16x16x32_bf16(a[mt], *p0, acc[mt][0], 0, 0, 0);
                acc[mt][1] = __builtin_amdgcn_mfma_f32_16x16x32_bf16(a[mt], *p1, acc[mt][1], 0, 0, 0);
            }
        }
        __syncthreads();
    }

    for (int mt = 0; mt < 4; ++mt) {
        int rbase = node0 + mt * 16 + q * 4;
        for (int r = 0; r < 4; ++r) {
            int rr = rbase + r;
            if (rr >= N) continue;
            float e = ex ? ex[rr] : 1.0f;
            for (int nt = 0; nt < 2; ++nt) {
                float v = acc[mt][nt][r];
                if (relu) v = fmaxf(v, 0.0f);
                v *= e;
                int col = n_off + nt * 16 + m16;
                if (obf) obf[(size_t)rr * 128 + col] = f2bf(v);
                else     of32[(size_t)rr * 128 + col] = v;
            }
        }
    }
}

// ---------------- launch ----------------

extern "C" void kernel_launch(void* const* d_in, const int* in_sizes, int n_in,
                              void* d_out, int out_size, void* d_ws, size_t ws_size,
                              hipStream_t stream) {
    const float* attr = (const float*)d_in[0];
    const float* cc   = (const float*)d_in[1];
    const float* bl   = (const float*)d_in[2];
    const float* ex   = (const float*)d_in[3];
    const float* w_in = (const float*)d_in[4];
    const float* b_in = (const float*)d_in[5];
    const float* w1s  = (const float*)d_in[6];
    const float* b1s  = (const float*)d_in[7];
    const float* w1n  = (const float*)d_in[8];
    const float* b1n  = (const float*)d_in[9];
    const float* w2s  = (const float*)d_in[10];
    const float* b2s  = (const float*)d_in[11];
    const float* w2n  = (const float*)d_in[12];
    const float* b2n  = (const float*)d_in[13];
    const int*   eidx = (const int*)d_in[14];

    int N = in_sizes[3];
    int ATTR = in_sizes[0] / N;
    int E = in_sizes[14] / 2;
    int Npad = ((N + 63) / 64) * 64;
    int nchunk = (N + 511) / 512;                  // 98
    int ntilesE = (E + BTILE - 1) / BTILE;         // 196
    int nbin = ntilesE < 256 ? ntilesE : 256;
    int gblk = Npad / 64;                          // 782

    char* ws = (char*)d_ws;
    size_t off = 0;
    auto alloc = [&](size_t bytes) -> char* {
        off = (off + 255) & ~(size_t)255;
        char* p = ws + off;
        off += bytes;
        return p;
    };
    unsigned short* x1 = (unsigned short*)alloc((size_t)Npad * 128 * 2);
    unsigned short* x2 = (unsigned short*)alloc((size_t)Npad * 128 * 2);
    unsigned short* nm = (unsigned short*)alloc((size_t)Npad * 128 * 2);
    int* colv        = (int*)alloc((size_t)nchunk * CHUNK_CAP * 4);
    unsigned* packed = (unsigned*)alloc((size_t)nchunk * CHUNK_CAP * 4);
    uint2* rows2     = (uint2*)alloc((size_t)N * 8);
    int* cursor      = (int*)alloc(128 * 4);
    unsigned short* wb = (unsigned short*)alloc((size_t)4 * 16384 * 2);
    float* biasf     = (float*)alloc(256 * 4);

    hipMemsetAsync(cursor, 0, 128 * sizeof(int), stream);

    // K1: edge binning | weight prep | layer-0 GEMM (fused x0 build)
    gemm0_bin<<<nbin + NPREP + gblk, 256, 0, stream>>>(
        attr, cc, bl, ex, w_in, b_in, x1,
        eidx, cursor, packed,
        w1s, w1n, w2s, w2n, b1s, b1n, b2s, b2n, wb, biasf,
        N, ATTR, E, ntilesE, nbin);
    // K2: CSR finalize
    chunk_csr<<<nchunk, 256, 0, stream>>>(packed, cursor, rows2, colv, N);
    // K3: nm1 = segment_mean(x1)
    agg_mean<<<(N + 3) / 4, 256, 0, stream>>>(x1, rows2, colv, nm, N);
    // K4: x2 = relu(x1 @ W1s^T + nm1 @ W1n^T + b1) * exist
    gemm_fused<<<gblk, 256, 0, stream>>>(x1, nm, wb, wb + 16384,
                                         biasf, ex, x2, (float*)nullptr, N, 1);
    // K5: nm2 = segment_mean(x2)
    agg_mean<<<(N + 3) / 4, 256, 0, stream>>>(x2, rows2, colv, nm, N);
    // K6: out = (x2 @ W2s^T + nm2 @ W2n^T + b2) * exist   (fp32 out)
    gemm_fused<<<gblk, 256, 0, stream>>>(x2, nm, wb + 2 * 16384, wb + 3 * 16384,
                                         biasf + 128, ex, (unsigned short*)nullptr,
                                         (float*)d_out, N, 0);
}